// Round 1
// baseline (710.163 us; speedup 1.0000x reference)
//
#include <hip/hip_runtime.h>
#include <cstdint>

#define B_ 8
#define A_ 120000
#define C_ 80
#define M_ 24
#define APB 64   // anchors per block

// ws layout (floats): [0..7] cls_sum[b], [8..15] reg_sum[b], [16..23] n_pos[b]

__global__ __launch_bounds__(256) void focal_main(
    const float* __restrict__ cls,
    const float* __restrict__ regs,
    const float* __restrict__ anchors,
    const float* __restrict__ annots,
    float* __restrict__ ws)
{
    const int b   = blockIdx.y;
    const int a0  = blockIdx.x * APB;
    const int tid = threadIdx.x;

    __shared__ float s_annot[M_ * 5];
    __shared__ int   s_meta[APB];   // -2 ignore, -1 negative, >=0 positive class label
    __shared__ float s_red[4];

    if (tid < M_ * 5) s_annot[tid] = annots[b * M_ * 5 + tid];
    __syncthreads();

    float reg_part = 0.0f;
    float pos_part = 0.0f;

    if (tid < APB) {
        const int a = a0 + tid;
        const float4 ab = *reinterpret_cast<const float4*>(anchors + (size_t)a * 4);
        const float ax1 = ab.x, ay1 = ab.y, ax2 = ab.z, ay2 = ab.w;
        const float aw  = ax2 - ax1, ah = ay2 - ay1;
        const float acx = ax1 + 0.5f * aw, acy = ay1 + 0.5f * ah;
        const float a_area = aw * ah;

        float best = -1e30f;
        int bestm = 0;
        #pragma unroll
        for (int m = 0; m < M_; ++m) {
            const float gx1 = s_annot[m * 5 + 0], gy1 = s_annot[m * 5 + 1];
            const float gx2 = s_annot[m * 5 + 2], gy2 = s_annot[m * 5 + 3];
            const float lab = s_annot[m * 5 + 4];
            const float g_area = (gx2 - gx1) * (gy2 - gy1);
            float iw = fminf(ax2, gx2) - fmaxf(ax1, gx1); iw = fmaxf(iw, 0.0f);
            float ih = fminf(ay2, gy2) - fmaxf(ay1, gy1); ih = fmaxf(ih, 0.0f);
            const float inter = iw * ih;
            const float uni = fmaxf(a_area + g_area - inter, 1e-6f);
            float iou = inter / uni;
            iou = (lab >= 0.0f) ? iou : -1.0f;     // invalid GT -> -1
            if (iou > best) { best = iou; bestm = m; }   // strict > == first-max argmax
        }

        const bool pos    = best >= 0.5f;
        const bool ignore = (best >= 0.4f) && !pos;
        const int  lab    = (int)s_annot[bestm * 5 + 4];
        s_meta[tid] = ignore ? -2 : (pos ? lab : -1);

        if (pos) {
            const float4 rv = *reinterpret_cast<const float4*>(regs + ((size_t)b * A_ + a) * 4);
            const float gx1 = s_annot[bestm * 5 + 0], gy1 = s_annot[bestm * 5 + 1];
            const float gx2 = s_annot[bestm * 5 + 2], gy2 = s_annot[bestm * 5 + 3];
            const float gw  = fmaxf(gx2 - gx1, 1.0f);
            const float gh  = fmaxf(gy2 - gy1, 1.0f);
            const float gcx = gx1 + 0.5f * (gx2 - gx1);
            const float gcy = gy1 + 0.5f * (gy2 - gy1);
            const float t0 = (gcx - acx) / aw * 10.0f;   // /0.1
            const float t1 = (gcy - acy) / ah * 10.0f;
            const float t2 = __logf(gw / aw) * 5.0f;     // /0.2
            const float t3 = __logf(gh / ah) * 5.0f;
            const float d0 = fabsf(t0 - rv.x), d1 = fabsf(t1 - rv.y);
            const float d2 = fabsf(t2 - rv.z), d3 = fabsf(t3 - rv.w);
            const float th = 1.0f / 9.0f, sub = 0.5f / 9.0f;
            float s;
            s  = (d0 <= th) ? 4.5f * d0 * d0 : d0 - sub;
            s += (d1 <= th) ? 4.5f * d1 * d1 : d1 - sub;
            s += (d2 <= th) ? 4.5f * d2 * d2 : d2 - sub;
            s += (d3 <= th) ? 4.5f * d3 * d3 : d3 - sub;
            reg_part = s;
            pos_part = 1.0f;
        }
    }

    // wave 0 holds all per-anchor partials (tid<64) -> reduce within wave 0
    if (tid < 64) {
        for (int off = 32; off > 0; off >>= 1) {
            reg_part += __shfl_down(reg_part, off, 64);
            pos_part += __shfl_down(pos_part, off, 64);
        }
        if (tid == 0) {
            atomicAdd(&ws[8 + b],  reg_part);
            atomicAdd(&ws[16 + b], pos_part);
        }
    }
    __syncthreads();   // s_meta visible to all

    // Phase 2: focal classification loss over this block's 64x80 cls slab
    const float4* cp4 = reinterpret_cast<const float4*>(cls + ((size_t)b * A_ + a0) * C_);
    constexpr int NV = APB * C_ / 4;   // 1280 vec4s
    float loc = 0.0f;
    for (int i = tid; i < NV; i += 256) {
        const float4 v = cp4[i];
        const int e0 = i * 4;
        const int al = e0 / C_;          // C_=80 is a multiple of 4: vec4 never spans anchors
        const int meta = s_meta[al];
        if (meta == -2) continue;        // ignored anchor: 0 contribution
        const int c0 = e0 - al * C_;
        const float pv[4] = {v.x, v.y, v.z, v.w};
        #pragma unroll
        for (int j = 0; j < 4; ++j) {
            float p = fminf(fmaxf(pv[j], 1e-4f), 1.0f - 1e-4f);
            const bool ip = (c0 + j == meta);   // positive anchor AND its class
            const float w  = ip ? 0.25f * (1.0f - p) * (1.0f - p) : 0.75f * p * p;
            const float ce = -__logf(ip ? p : (1.0f - p));
            loc += w * ce;
        }
    }

    // block reduce loc -> atomicAdd per image
    for (int off = 32; off > 0; off >>= 1) loc += __shfl_down(loc, off, 64);
    const int wid = tid >> 6;
    if ((tid & 63) == 0) s_red[wid] = loc;
    __syncthreads();
    if (tid == 0) {
        atomicAdd(&ws[b], s_red[0] + s_red[1] + s_red[2] + s_red[3]);
    }
}

__global__ void focal_final(const float* __restrict__ ws, float* __restrict__ out)
{
    if (threadIdx.x == 0) {
        float cm = 0.0f, rm = 0.0f;
        for (int b = 0; b < B_; ++b) {
            const float np = ws[16 + b];
            cm += ws[b] / fmaxf(np, 1.0f);
            rm += (np > 0.0f) ? ws[8 + b] / (np * 4.0f) : 0.0f;
        }
        out[0] = cm * (1.0f / B_);
        out[1] = rm * (1.0f / B_);
    }
}

extern "C" void kernel_launch(void* const* d_in, const int* in_sizes, int n_in,
                              void* d_out, int out_size, void* d_ws, size_t ws_size,
                              hipStream_t stream)
{
    const float* cls     = (const float*)d_in[0];
    const float* regs    = (const float*)d_in[1];
    const float* anchors = (const float*)d_in[2];
    const float* annots  = (const float*)d_in[3];
    float* ws  = (float*)d_ws;
    float* out = (float*)d_out;

    hipMemsetAsync(d_ws, 0, 24 * sizeof(float), stream);   // zero accumulators (ws is poisoned)

    dim3 grid(A_ / APB, B_);   // 120000/64 = 1875 exact
    focal_main<<<grid, 256, 0, stream>>>(cls, regs, anchors, annots, ws);
    focal_final<<<1, 64, 0, stream>>>(ws, out);
}

// Round 4
// 449.553 us; speedup vs baseline: 1.5797x; 1.5797x over previous
//
#include <hip/hip_runtime.h>
#include <cstdint>

#define B_ 8
#define A_ 120000
#define C_ 80
#define M_ 24
#define APB 250                 // anchors per block; 120000/250 = 480 exact
#define NVB (APB * C_ / 4)      // 5000 float4s per block

// ws layout (floats): [0..7] cls_sum[b], [8..15] reg_sum[b], [16..23] n_pos[b]

__global__ __launch_bounds__(256) void focal_main(
    const float* __restrict__ cls,
    const float* __restrict__ regs,
    const float* __restrict__ anchors,
    const float* __restrict__ annots,
    float* __restrict__ ws)
{
    const int b   = blockIdx.y;
    const int a0  = blockIdx.x * APB;
    const int tid = threadIdx.x;

    __shared__ float s_annot[M_ * 5];
    __shared__ float s_mask[APB];          // 0 = ignored anchor, 1 = contributes
    __shared__ float s_redc[4], s_redr[4], s_redp[4];

    if (tid < M_ * 5) s_annot[tid] = annots[b * M_ * 5 + tid];
    __syncthreads();

    float cls_part = 0.0f, reg_part = 0.0f, pos_part = 0.0f;
    const float PLO = 1e-4f, PHI = 1.0f - 1e-4f;

    // ---- Phase 1: one anchor per thread (tid < 250) ----
    if (tid < APB) {
        const int a = a0 + tid;
        const float4 ab = *reinterpret_cast<const float4*>(anchors + (size_t)a * 4);
        const float ax1 = ab.x, ay1 = ab.y, ax2 = ab.z, ay2 = ab.w;
        const float aw  = ax2 - ax1, ah = ay2 - ay1;
        const float acx = ax1 + 0.5f * aw, acy = ay1 + 0.5f * ah;
        const float a_area = aw * ah;

        float best = -1e30f;
        int bestm = 0;
        #pragma unroll
        for (int m = 0; m < M_; ++m) {
            const float gx1 = s_annot[m * 5 + 0], gy1 = s_annot[m * 5 + 1];
            const float gx2 = s_annot[m * 5 + 2], gy2 = s_annot[m * 5 + 3];
            const float lab = s_annot[m * 5 + 4];
            const float g_area = (gx2 - gx1) * (gy2 - gy1);
            float iw = fminf(ax2, gx2) - fmaxf(ax1, gx1); iw = fmaxf(iw, 0.0f);
            float ih = fminf(ay2, gy2) - fmaxf(ay1, gy1); ih = fmaxf(ih, 0.0f);
            const float inter = iw * ih;
            const float uni = fmaxf(a_area + g_area - inter, 1e-6f);
            float iou = inter * __builtin_amdgcn_rcpf(uni);   // fast rcp, ~1e-7 rel
            iou = (lab >= 0.0f) ? iou : -1.0f;
            if (iou > best) { best = iou; bestm = m; }        // strict > == first-max argmax
        }

        const bool pos    = best >= 0.5f;
        const bool ignore = (best >= 0.4f) && !pos;
        const int  lab    = (int)s_annot[bestm * 5 + 4];
        s_mask[tid] = ignore ? 0.0f : 1.0f;

        if (pos) {
            pos_part = 1.0f;
            // --- regression smooth-L1 ---
            const float4 rv = *reinterpret_cast<const float4*>(regs + ((size_t)b * A_ + a) * 4);
            const float gx1 = s_annot[bestm * 5 + 0], gy1 = s_annot[bestm * 5 + 1];
            const float gx2 = s_annot[bestm * 5 + 2], gy2 = s_annot[bestm * 5 + 3];
            const float gw  = fmaxf(gx2 - gx1, 1.0f);
            const float gh  = fmaxf(gy2 - gy1, 1.0f);
            const float gcx = gx1 + 0.5f * (gx2 - gx1);
            const float gcy = gy1 + 0.5f * (gy2 - gy1);
            const float inv_aw = __builtin_amdgcn_rcpf(aw);
            const float inv_ah = __builtin_amdgcn_rcpf(ah);
            const float t0 = (gcx - acx) * inv_aw * 10.0f;    // /0.1
            const float t1 = (gcy - acy) * inv_ah * 10.0f;
            const float t2 = __logf(gw * inv_aw) * 5.0f;      // /0.2
            const float t3 = __logf(gh * inv_ah) * 5.0f;
            const float d0 = fabsf(t0 - rv.x), d1 = fabsf(t1 - rv.y);
            const float d2 = fabsf(t2 - rv.z), d3 = fabsf(t3 - rv.w);
            const float th = 1.0f / 9.0f, sub = 0.5f / 9.0f;
            float s;
            s  = (d0 <= th) ? 4.5f * d0 * d0 : d0 - sub;
            s += (d1 <= th) ? 4.5f * d1 * d1 : d1 - sub;
            s += (d2 <= th) ? 4.5f * d2 * d2 : d2 - sub;
            s += (d3 <= th) ? 4.5f * d3 * d3 : d3 - sub;
            reg_part = s;

            // --- positive-class correction vs the negative baseline of phase 2 ---
            float p = cls[((size_t)b * A_ + a) * C_ + lab];
            p = fminf(fmaxf(p, PLO), PHI);
            const float q = 1.0f - p;
            const float pos_term = 0.25f * q * q * (-__logf(p));
            const float neg_term = 0.75f * p * p * (-__logf(q));
            cls_part = pos_term - neg_term;
        }
    }
    __syncthreads();   // s_mask ready

    // ---- Phase 2: branch-free negative baseline over the 250x80 slab ----
    // contribution per element: 0.75 * p^2 * (-ln(1-p)); row-masked for ignores.
    const float4* cp4 = reinterpret_cast<const float4*>(cls + ((size_t)b * A_ + a0) * C_);
    const float NEG_SCALE = -0.75f * 0.69314718056f;   // p^2*log2(q) -> 0.75*p^2*(-ln q)
    #pragma unroll 4
    for (int i = tid; i < NVB; i += 256) {
        const float4 v = cp4[i];
        const int   al = i / 20;            // 20 vec4s per anchor row (magic-mul)
        const float m  = s_mask[al];
        float c = 0.0f, p, q;
        p = fminf(fmaxf(v.x, PLO), PHI); q = 1.0f - p; c = fmaf(p * p, __log2f(q), c);
        p = fminf(fmaxf(v.y, PLO), PHI); q = 1.0f - p; c = fmaf(p * p, __log2f(q), c);
        p = fminf(fmaxf(v.z, PLO), PHI); q = 1.0f - p; c = fmaf(p * p, __log2f(q), c);
        p = fminf(fmaxf(v.w, PLO), PHI); q = 1.0f - p; c = fmaf(p * p, __log2f(q), c);
        cls_part = fmaf(m * c, NEG_SCALE, cls_part);
    }

    // ---- block reduce (3 values) ----
    for (int off = 32; off > 0; off >>= 1) {
        cls_part += __shfl_down(cls_part, off, 64);
        reg_part += __shfl_down(reg_part, off, 64);
        pos_part += __shfl_down(pos_part, off, 64);
    }
    const int wid = tid >> 6;
    if ((tid & 63) == 0) { s_redc[wid] = cls_part; s_redr[wid] = reg_part; s_redp[wid] = pos_part; }
    __syncthreads();
    if (tid == 0) {
        atomicAdd(&ws[b],      s_redc[0] + s_redc[1] + s_redc[2] + s_redc[3]);
        atomicAdd(&ws[8 + b],  s_redr[0] + s_redr[1] + s_redr[2] + s_redr[3]);
        atomicAdd(&ws[16 + b], s_redp[0] + s_redp[1] + s_redp[2] + s_redp[3]);
    }
}

__global__ void focal_final(const float* __restrict__ ws, float* __restrict__ out)
{
    if (threadIdx.x == 0) {
        float cm = 0.0f, rm = 0.0f;
        for (int b = 0; b < B_; ++b) {
            const float np = ws[16 + b];
            cm += ws[b] / fmaxf(np, 1.0f);
            rm += (np > 0.0f) ? ws[8 + b] / (np * 4.0f) : 0.0f;
        }
        out[0] = cm * (1.0f / B_);
        out[1] = rm * (1.0f / B_);
    }
}

extern "C" void kernel_launch(void* const* d_in, const int* in_sizes, int n_in,
                              void* d_out, int out_size, void* d_ws, size_t ws_size,
                              hipStream_t stream)
{
    const float* cls     = (const float*)d_in[0];
    const float* regs    = (const float*)d_in[1];
    const float* anchors = (const float*)d_in[2];
    const float* annots  = (const float*)d_in[3];
    float* ws  = (float*)d_ws;
    float* out = (float*)d_out;

    hipMemsetAsync(d_ws, 0, 24 * sizeof(float), stream);   // zero accumulators

    dim3 grid(A_ / APB, B_);   // (480, 8)
    focal_main<<<grid, 256, 0, stream>>>(cls, regs, anchors, annots, ws);
    focal_final<<<1, 64, 0, stream>>>(ws, out);
}